// Round 1
// baseline (12096.969 us; speedup 1.0000x reference)
//
#include <hip/hip_runtime.h>
#include <math.h>

// PhasedLSTM: B=64, T=512, H=768. fp32 in/out.
// Strategy: persistent cooperative-style kernel, 1 grid barrier per timestep.
//   gates GEMM: [x_t | h] (64x1536) @ WcombT^T (1536x3072) in bf16 MFMA.
//   Block j owns hidden dims d0..d0+7 across all 4 gate groups -> elementwise
//   update is block-local; c,h state in LDS (fp32, full precision).

#define HDIM 768
#define BDIM 64
#define TDIM 512
#define G_BLOCKS 96
#define ND 8   // hidden dims per block (768/96)

typedef float f32x4 __attribute__((ext_vector_type(4)));
typedef __bf16 bf16x8 __attribute__((ext_vector_type(8)));

// workspace layout (bytes)
#define OFF_BAR   0
#define OFF_HBUF0 256
#define OFF_HBUF1 (256 + 98304)
#define OFF_KTAB  (256 + 2*98304)                       // 196864
#define OFF_WT    (OFF_KTAB + (size_t)512*768*4)        // 1769728
#define OFF_XB    (OFF_WT + (size_t)3072*1536*2)        // 11206912
#define WS_NEED_FULL (OFF_XB + (size_t)512*64*768*2)    // 61538560

// ---------------- prep kernels ----------------

// WcombT[n][k], n in [0,3072) = gate col (i,f,o rows of Wsum/Usum, then c-gate),
// k in [0,1536): k<768 from W (x path), k>=768 from U (h path). bf16, transposed
// so MFMA B-fragments (8 consecutive k, fixed n) are contiguous 16B loads.
__global__ void k_wcomb(const float* __restrict__ W, const float* __restrict__ U,
                        __bf16* __restrict__ WT) {
  __shared__ __bf16 tile[32][33];
  int tk = blockIdx.x % 48;   // k tile (1536/32)
  int tn = blockIdx.x / 48;   // n tile (3072/32)
  int tx = threadIdx.x & 31, ty = threadIdx.x >> 5; // 32 x 8
  int k0 = tk * 32, n0 = tn * 32;
#pragma unroll
  for (int i = 0; i < 4; ++i) {
    int k = k0 + ty + 8 * i;
    int n = n0 + tx;
    const float* M = (k < 768) ? W : U;
    int r = (k < 768) ? k : k - 768;
    float v;
    if (n < 2304)
      v = M[(size_t)r * 3072 + n] + M[(size_t)(768 + r) * 3072 + n] +
          M[(size_t)(1536 + r) * 3072 + n];
    else
      v = M[(size_t)(2304 + r) * 3072 + n];
    tile[ty + 8 * i][tx] = (__bf16)v;
  }
  __syncthreads();
#pragma unroll
  for (int i = 0; i < 4; ++i) {
    int n = n0 + ty + 8 * i;
    int k = k0 + tx;
    WT[(size_t)n * 1536 + k] = tile[tx][ty + 8 * i];
  }
}

// time-gate table k(t,d), exact replica of reference formula in fp32
__global__ void k_ktab(const float* __restrict__ tau, const float* __restrict__ shift,
                       float* __restrict__ kT) {
  int idx = blockIdx.x * 256 + threadIdx.x;  // t*768 + d
  int d = idx % 768, t = idx / 768;
  float bb = tau[d];
  float a = (float)t - shift[d];
  const float PI = 3.14159265358979323846f;
  float fm = bb / PI * atanf(tanf(PI * (a / bb - 0.5f))) + bb * 0.5f;
  float phi = fm / (bb + 1e-8f);
  float kv;
  if (phi < 0.5f * 0.05f)      kv = 2.0f * phi / 0.05f;
  else if (phi < 0.05f)        kv = 2.0f - 2.0f * phi / 0.05f;
  else                         kv = 0.001f * phi;
  kT[idx] = kv;
}

// x (B,T,H) fp32 -> xb (T,B,H) bf16
__global__ void k_xb(const float* __restrict__ x, __bf16* __restrict__ xb) {
  int idx = blockIdx.x * 256 + threadIdx.x;  // (t*64+b)*768 + k
  int k = idx % 768;
  int tb = idx / 768;
  int b = tb % 64, t = tb / 64;
  xb[idx] = (__bf16)x[((size_t)b * 512 + t) * 768 + k];
}

// ---------------- grid barrier ----------------
__device__ __forceinline__ void gridbar(int* cnt, int* gen) {
  __syncthreads();                 // waitcnt vm(0): all our global writes in L2
  if (threadIdx.x == 0) {
    __threadfence();               // release: flush L2 -> device visible
    int g = __hip_atomic_load(gen, __ATOMIC_RELAXED, __HIP_MEMORY_SCOPE_AGENT);
    int a = __hip_atomic_fetch_add(cnt, 1, __ATOMIC_RELAXED, __HIP_MEMORY_SCOPE_AGENT);
    if (a == G_BLOCKS - 1) {
      __hip_atomic_store(cnt, 0, __ATOMIC_RELAXED, __HIP_MEMORY_SCOPE_AGENT);
      __hip_atomic_fetch_add(gen, 1, __ATOMIC_RELAXED, __HIP_MEMORY_SCOPE_AGENT);
    } else {
      while (__hip_atomic_load(gen, __ATOMIC_RELAXED, __HIP_MEMORY_SCOPE_AGENT) == g) {
        __builtin_amdgcn_s_sleep(1);
      }
    }
    __threadfence();               // acquire: inv L1/L2 so fresh h is visible
  }
  __syncthreads();
}

// ---------------- persistent recurrent kernel ----------------
__global__ __launch_bounds__(256, 1)
void k_lstm(const __bf16* __restrict__ xb, const float* __restrict__ xf, int use_xb,
            const __bf16* __restrict__ WT, const float* __restrict__ kT,
            const float* __restrict__ bias, const float* __restrict__ wpeep,
            __bf16* h0buf, __bf16* h1buf, float* __restrict__ out, int* bar) {
  const int j = blockIdx.x, d0 = j * ND;
  const int tid = threadIdx.x;
  const int wave = tid >> 6, lane = tid & 63;
  const int mh = wave >> 1, kh = wave & 1;   // m-half (rows 32), K-half (768)
  const int quad = lane >> 4, l15 = lane & 15;

  __shared__ float gacc[2][64][36];   // [khalf][batch][32 gate cols + pad]
  __shared__ float cS[512], hS[512];  // block-local c,h state, fp32: [b*8 + dl]
  for (int s = tid; s < 512; s += 256) { cS[s] = 0.f; hS[s] = 0.f; }

  // elementwise-thread constants: d fixed per thread, b = eb0 + 32*rep
  const int edl = tid & 7, eb0 = tid >> 3;
  const int ed = d0 + edl;
  const float bi  = bias[ed],        bfv = bias[768 + ed];
  const float bo  = bias[1536 + ed], bcv = bias[2304 + ed];
  const float wpi = wpeep[ed], wpf = wpeep[768 + ed], wpo = wpeep[1536 + ed];

  // B-fragment base pointers (2 column tiles: [i|f] and [o|c])
  const int bc_ = l15 & 7, bg = l15 >> 3;
  const __bf16* bp0 = WT + ((size_t)((0 + bg) * 768 + d0 + bc_)) * 1536 + kh * 768 + quad * 8;
  const __bf16* bp1 = WT + ((size_t)((2 + bg) * 768 + d0 + bc_)) * 1536 + kh * 768 + quad * 8;
  const int r0 = mh * 32 + l15, r1 = r0 + 16;   // batch rows (A fragment m)

  __syncthreads();

  for (int t = 0; t < TDIM; ++t) {
    const __bf16* hcur = (t & 1) ? h1buf : h0buf;
    __bf16* hnxt = (t & 1) ? h0buf : h1buf;

    f32x4 a00 = {0,0,0,0}, a01 = {0,0,0,0}, a10 = {0,0,0,0}, a11 = {0,0,0,0};
    const __bf16 *A0, *A1;
    if (kh == 0) {
      A0 = xb + ((size_t)t * 64 + r0) * 768 + quad * 8;
      A1 = xb + ((size_t)t * 64 + r1) * 768 + quad * 8;
    } else {
      A0 = hcur + (size_t)r0 * 768 + quad * 8;
      A1 = hcur + (size_t)r1 * 768 + quad * 8;
    }
    const float* X0 = xf + ((size_t)r0 * 512 + t) * 768 + quad * 8;
    const float* X1 = xf + ((size_t)r1 * 512 + t) * 768 + quad * 8;

#pragma unroll 4
    for (int ks = 0; ks < 24; ++ks) {
      bf16x8 av0, av1;
      if (kh == 0 && !use_xb) {
#pragma unroll
        for (int q = 0; q < 8; ++q) {
          av0[q] = (__bf16)X0[ks * 32 + q];
          av1[q] = (__bf16)X1[ks * 32 + q];
        }
      } else {
        av0 = *(const bf16x8*)(A0 + ks * 32);
        av1 = *(const bf16x8*)(A1 + ks * 32);
      }
      bf16x8 bv0 = *(const bf16x8*)(bp0 + ks * 32);
      bf16x8 bv1 = *(const bf16x8*)(bp1 + ks * 32);
      a00 = __builtin_amdgcn_mfma_f32_16x16x32_bf16(av0, bv0, a00, 0, 0, 0);
      a01 = __builtin_amdgcn_mfma_f32_16x16x32_bf16(av0, bv1, a01, 0, 0, 0);
      a10 = __builtin_amdgcn_mfma_f32_16x16x32_bf16(av1, bv0, a10, 0, 0, 0);
      a11 = __builtin_amdgcn_mfma_f32_16x16x32_bf16(av1, bv1, a11, 0, 0, 0);
    }

    // C/D layout: col = lane&15, row = quad*4 + reg (m89/m91-verified)
#pragma unroll
    for (int r = 0; r < 4; ++r) {
      gacc[kh][mh * 32 + quad * 4 + r][l15]           = a00[r];
      gacc[kh][mh * 32 + quad * 4 + r][16 + l15]      = a01[r];
      gacc[kh][mh * 32 + 16 + quad * 4 + r][l15]      = a10[r];
      gacc[kh][mh * 32 + 16 + quad * 4 + r][16 + l15] = a11[r];
    }
    __syncthreads();

    float kt = kT[t * 768 + ed];
#pragma unroll
    for (int rep = 0; rep < 2; ++rep) {
      int b = eb0 + 32 * rep;
      int s = b * 8 + edl;
      float c_prev = cS[s], h_prev = hS[s];
      float gi = gacc[0][b][edl]      + gacc[1][b][edl]      + bi  + wpi * c_prev;
      float gf = gacc[0][b][8 + edl]  + gacc[1][b][8 + edl]  + bfv + wpf * c_prev;
      float go = gacc[0][b][16 + edl] + gacc[1][b][16 + edl] + bo  + wpo * c_prev;
      float gc = gacc[0][b][24 + edl] + gacc[1][b][24 + edl] + bcv;
      float iv = 1.f / (1.f + expf(-gi));
      float fv = 1.f / (1.f + expf(-gf));
      float ov = 1.f / (1.f + expf(-go));
      float cp = fv * c_prev + iv * tanhf(gc);
      float cn = kt * cp + (1.f - kt) * c_prev;
      float hp = tanhf(cp) * ov;
      float hn = kt * hp + (1.f - kt) * h_prev;
      cS[s] = cn; hS[s] = hn;
      out[((size_t)b * 512 + t) * 768 + ed] = hn;
      hnxt[b * 768 + ed] = (__bf16)hn;
    }

    gridbar(&bar[0], &bar[1]);
  }
}

// ---------------- launch ----------------
extern "C" void kernel_launch(void* const* d_in, const int* in_sizes, int n_in,
                              void* d_out, int out_size, void* d_ws, size_t ws_size,
                              hipStream_t stream) {
  const float* x     = (const float*)d_in[0];
  const float* W     = (const float*)d_in[1];
  const float* U     = (const float*)d_in[2];
  const float* bias  = (const float*)d_in[3];
  const float* wpeep = (const float*)d_in[4];
  const float* tau   = (const float*)d_in[5];
  const float* shift = (const float*)d_in[6];
  float* out = (float*)d_out;
  char* ws = (char*)d_ws;

  int*    bar = (int*)(ws + OFF_BAR);
  __bf16* hb0 = (__bf16*)(ws + OFF_HBUF0);
  __bf16* hb1 = (__bf16*)(ws + OFF_HBUF1);
  float*  kT  = (float*)(ws + OFF_KTAB);
  __bf16* WT  = (__bf16*)(ws + OFF_WT);
  __bf16* xb  = (__bf16*)(ws + OFF_XB);
  int use_xb = (ws_size >= WS_NEED_FULL) ? 1 : 0;

  // zero barrier + both h buffers (h0 = 0)
  hipMemsetAsync(ws, 0, OFF_KTAB, stream);
  k_wcomb<<<48 * 96, 256, 0, stream>>>(W, U, WT);
  k_ktab<<<(512 * 768) / 256, 256, 0, stream>>>(tau, shift, kT);
  if (use_xb) k_xb<<<(512 * 64 * 768) / 256, 256, 0, stream>>>(x, xb);
  k_lstm<<<G_BLOCKS, 256, 0, stream>>>(xb, x, use_xb, WT, kT, bias, wpeep,
                                       hb0, hb1, out, bar);
}

// Round 2
// 8845.882 us; speedup vs baseline: 1.3675x; 1.3675x over previous
//
#include <hip/hip_runtime.h>
#include <math.h>

// PhasedLSTM: B=64, T=512, H=768. fp32 in/out.
// Persistent kernel, 1 grid barrier per timestep.
//   gates GEMM: [x_t | h] (64x1536) @ WcombT^T (1536x3072) in bf16 MFMA.
//   Block j owns hidden dims d0..d0+7 across all 4 gate groups.
// R1->R2: removed __threadfence() (full L2 wb/inv scans, ~20us/step);
//   h exchange now uses targeted coherent sc0 sc1 loads/stores that bypass
//   L1/L2 and hit the (memory-side, coherent) Infinity Cache. WT/xb stay
//   L2-resident across steps.

#define HDIM 768
#define BDIM 64
#define TDIM 512
#define G_BLOCKS 96
#define ND 8   // hidden dims per block (768/96)

typedef float f32x4 __attribute__((ext_vector_type(4)));
typedef __bf16 bf16x8 __attribute__((ext_vector_type(8)));
typedef int i32x4 __attribute__((ext_vector_type(4)));

// workspace layout (bytes)
#define OFF_BAR   0
#define OFF_HBUF0 256
#define OFF_HBUF1 (256 + 98304)
#define OFF_KTAB  (256 + 2*98304)                       // 196864
#define OFF_WT    (OFF_KTAB + (size_t)512*768*4)        // 1769728
#define OFF_XB    (OFF_WT + (size_t)3072*1536*2)        // 11206912
#define WS_NEED_FULL (OFF_XB + (size_t)512*64*768*2)    // 61538560

// ---------------- prep kernels ----------------

__global__ void k_wcomb(const float* __restrict__ W, const float* __restrict__ U,
                        __bf16* __restrict__ WT) {
  __shared__ __bf16 tile[32][33];
  int tk = blockIdx.x % 48;   // k tile (1536/32)
  int tn = blockIdx.x / 48;   // n tile (3072/32)
  int tx = threadIdx.x & 31, ty = threadIdx.x >> 5; // 32 x 8
  int k0 = tk * 32, n0 = tn * 32;
#pragma unroll
  for (int i = 0; i < 4; ++i) {
    int k = k0 + ty + 8 * i;
    int n = n0 + tx;
    const float* M = (k < 768) ? W : U;
    int r = (k < 768) ? k : k - 768;
    float v;
    if (n < 2304)
      v = M[(size_t)r * 3072 + n] + M[(size_t)(768 + r) * 3072 + n] +
          M[(size_t)(1536 + r) * 3072 + n];
    else
      v = M[(size_t)(2304 + r) * 3072 + n];
    tile[ty + 8 * i][tx] = (__bf16)v;
  }
  __syncthreads();
#pragma unroll
  for (int i = 0; i < 4; ++i) {
    int n = n0 + ty + 8 * i;
    int k = k0 + tx;
    WT[(size_t)n * 1536 + k] = tile[tx][ty + 8 * i];
  }
}

__global__ void k_ktab(const float* __restrict__ tau, const float* __restrict__ shift,
                       float* __restrict__ kT) {
  int idx = blockIdx.x * 256 + threadIdx.x;  // t*768 + d
  int d = idx % 768, t = idx / 768;
  float bb = tau[d];
  float a = (float)t - shift[d];
  const float PI = 3.14159265358979323846f;
  float fm = bb / PI * atanf(tanf(PI * (a / bb - 0.5f))) + bb * 0.5f;
  float phi = fm / (bb + 1e-8f);
  float kv;
  if (phi < 0.5f * 0.05f)      kv = 2.0f * phi / 0.05f;
  else if (phi < 0.05f)        kv = 2.0f - 2.0f * phi / 0.05f;
  else                         kv = 0.001f * phi;
  kT[idx] = kv;
}

__global__ void k_xb(const float* __restrict__ x, __bf16* __restrict__ xb) {
  int idx = blockIdx.x * 256 + threadIdx.x;  // (t*64+b)*768 + k
  int k = idx % 768;
  int tb = idx / 768;
  int b = tb % 64, t = tb / 64;
  xb[idx] = (__bf16)x[((size_t)b * 512 + t) * 768 + k];
}

// ---------------- coherent access helpers ----------------
__device__ __forceinline__ i32x4 load_coherent_16(const void* p) {
  i32x4 r;
  asm volatile("global_load_dwordx4 %0, %1, off sc0 sc1"
               : "=v"(r) : "v"(p) : "memory");
  return r;
}
__device__ __forceinline__ void store_coherent_short(void* p, unsigned v) {
  asm volatile("global_store_short %0, %1, off sc0 sc1"
               :: "v"(p), "v"(v) : "memory");
}
__device__ __forceinline__ void waitcnt_vm0() {
  asm volatile("s_waitcnt vmcnt(0)" ::: "memory");
}

// ---------------- grid barrier (no full fences) ----------------
__device__ __forceinline__ void gridbar(int* cnt, int* gen) {
  __syncthreads();
  if (threadIdx.x == 0) {
    int g = __hip_atomic_load(gen, __ATOMIC_RELAXED, __HIP_MEMORY_SCOPE_AGENT);
    int a = __hip_atomic_fetch_add(cnt, 1, __ATOMIC_RELAXED, __HIP_MEMORY_SCOPE_AGENT);
    if (a == G_BLOCKS - 1) {
      __hip_atomic_store(cnt, 0, __ATOMIC_RELAXED, __HIP_MEMORY_SCOPE_AGENT);
      __hip_atomic_fetch_add(gen, 1, __ATOMIC_RELAXED, __HIP_MEMORY_SCOPE_AGENT);
    } else {
      while (__hip_atomic_load(gen, __ATOMIC_RELAXED, __HIP_MEMORY_SCOPE_AGENT) == g) {
        __builtin_amdgcn_s_sleep(1);
      }
    }
  }
  __syncthreads();
}

// ---------------- persistent recurrent kernel ----------------
__global__ __launch_bounds__(256, 1)
void k_lstm(const __bf16* __restrict__ xb, const float* __restrict__ xf, int use_xb,
            const __bf16* __restrict__ WT, const float* __restrict__ kT,
            const float* __restrict__ bias, const float* __restrict__ wpeep,
            __bf16* h0buf, __bf16* h1buf, float* __restrict__ out, int* bar) {
  const int j = blockIdx.x, d0 = j * ND;
  const int tid = threadIdx.x;
  const int wave = tid >> 6, lane = tid & 63;
  const int mh = wave >> 1, kh = wave & 1;   // m-half (rows 32), K-half (768)
  const int quad = lane >> 4, l15 = lane & 15;

  __shared__ float gacc[2][64][36];   // [khalf][batch][32 gate cols + pad]
  __shared__ float cS[512], hS[512];  // block-local c,h state, fp32: [b*8 + dl]
  for (int s = tid; s < 512; s += 256) { cS[s] = 0.f; hS[s] = 0.f; }

  const int edl = tid & 7, eb0 = tid >> 3;
  const int ed = d0 + edl;
  const float bi  = bias[ed],        bfv = bias[768 + ed];
  const float bo  = bias[1536 + ed], bcv = bias[2304 + ed];
  const float wpi = wpeep[ed], wpf = wpeep[768 + ed], wpo = wpeep[1536 + ed];

  const int bc_ = l15 & 7, bg = l15 >> 3;
  const __bf16* bp0 = WT + ((size_t)((0 + bg) * 768 + d0 + bc_)) * 1536 + kh * 768 + quad * 8;
  const __bf16* bp1 = WT + ((size_t)((2 + bg) * 768 + d0 + bc_)) * 1536 + kh * 768 + quad * 8;
  const int r0 = mh * 32 + l15, r1 = r0 + 16;   // batch rows (A fragment m)

  __syncthreads();

  for (int t = 0; t < TDIM; ++t) {
    const __bf16* hcur = (t & 1) ? h1buf : h0buf;
    __bf16* hnxt = (t & 1) ? h0buf : h1buf;

    f32x4 a00 = {0,0,0,0}, a01 = {0,0,0,0}, a10 = {0,0,0,0}, a11 = {0,0,0,0};

    if (kh == 1) {
      // h path: coherent loads (bypass L1/L2 -> Infinity Cache, sees other
      // XCDs' writes from the previous step without any cache flush)
      const __bf16* A0 = hcur + (size_t)r0 * 768 + quad * 8;
      const __bf16* A1 = hcur + (size_t)r1 * 768 + quad * 8;
#pragma unroll
      for (int ch = 0; ch < 4; ++ch) {
        i32x4 ar0[6], ar1[6];
        bf16x8 bv0c[6], bv1c[6];
#pragma unroll
        for (int i = 0; i < 6; ++i) {
          int ks = ch * 6 + i;
          ar0[i] = load_coherent_16(A0 + ks * 32);
          ar1[i] = load_coherent_16(A1 + ks * 32);
        }
#pragma unroll
        for (int i = 0; i < 6; ++i) {
          int ks = ch * 6 + i;
          bv0c[i] = *(const bf16x8*)(bp0 + ks * 32);
          bv1c[i] = *(const bf16x8*)(bp1 + ks * 32);
        }
        waitcnt_vm0();
#pragma unroll
        for (int i = 0; i < 6; ++i) {
          bf16x8 av0 = __builtin_bit_cast(bf16x8, ar0[i]);
          bf16x8 av1 = __builtin_bit_cast(bf16x8, ar1[i]);
          a00 = __builtin_amdgcn_mfma_f32_16x16x32_bf16(av0, bv0c[i], a00, 0, 0, 0);
          a01 = __builtin_amdgcn_mfma_f32_16x16x32_bf16(av0, bv1c[i], a01, 0, 0, 0);
          a10 = __builtin_amdgcn_mfma_f32_16x16x32_bf16(av1, bv0c[i], a10, 0, 0, 0);
          a11 = __builtin_amdgcn_mfma_f32_16x16x32_bf16(av1, bv1c[i], a11, 0, 0, 0);
        }
      }
    } else {
      // x path: normal loads, stays L2-hot across steps
      const __bf16* A0 = xb + ((size_t)t * 64 + r0) * 768 + quad * 8;
      const __bf16* A1 = xb + ((size_t)t * 64 + r1) * 768 + quad * 8;
      const float* X0 = xf + ((size_t)r0 * 512 + t) * 768 + quad * 8;
      const float* X1 = xf + ((size_t)r1 * 512 + t) * 768 + quad * 8;
#pragma unroll 4
      for (int ks = 0; ks < 24; ++ks) {
        bf16x8 av0, av1;
        if (!use_xb) {
#pragma unroll
          for (int q = 0; q < 8; ++q) {
            av0[q] = (__bf16)X0[ks * 32 + q];
            av1[q] = (__bf16)X1[ks * 32 + q];
          }
        } else {
          av0 = *(const bf16x8*)(A0 + ks * 32);
          av1 = *(const bf16x8*)(A1 + ks * 32);
        }
        bf16x8 bv0 = *(const bf16x8*)(bp0 + ks * 32);
        bf16x8 bv1 = *(const bf16x8*)(bp1 + ks * 32);
        a00 = __builtin_amdgcn_mfma_f32_16x16x32_bf16(av0, bv0, a00, 0, 0, 0);
        a01 = __builtin_amdgcn_mfma_f32_16x16x32_bf16(av0, bv1, a01, 0, 0, 0);
        a10 = __builtin_amdgcn_mfma_f32_16x16x32_bf16(av1, bv0, a10, 0, 0, 0);
        a11 = __builtin_amdgcn_mfma_f32_16x16x32_bf16(av1, bv1, a11, 0, 0, 0);
      }
    }

    // C/D layout: col = lane&15, row = quad*4 + reg (m89/m91-verified)
#pragma unroll
    for (int r = 0; r < 4; ++r) {
      gacc[kh][mh * 32 + quad * 4 + r][l15]           = a00[r];
      gacc[kh][mh * 32 + quad * 4 + r][16 + l15]      = a01[r];
      gacc[kh][mh * 32 + 16 + quad * 4 + r][l15]      = a10[r];
      gacc[kh][mh * 32 + 16 + quad * 4 + r][16 + l15] = a11[r];
    }
    __syncthreads();

    float kt = kT[t * 768 + ed];
#pragma unroll
    for (int rep = 0; rep < 2; ++rep) {
      int b = eb0 + 32 * rep;
      int s = b * 8 + edl;
      float c_prev = cS[s], h_prev = hS[s];
      float gi = gacc[0][b][edl]      + gacc[1][b][edl]      + bi  + wpi * c_prev;
      float gf = gacc[0][b][8 + edl]  + gacc[1][b][8 + edl]  + bfv + wpf * c_prev;
      float go = gacc[0][b][16 + edl] + gacc[1][b][16 + edl] + bo  + wpo * c_prev;
      float gc = gacc[0][b][24 + edl] + gacc[1][b][24 + edl] + bcv;
      float iv = 1.f / (1.f + expf(-gi));
      float fv = 1.f / (1.f + expf(-gf));
      float ov = 1.f / (1.f + expf(-go));
      float cp = fv * c_prev + iv * tanhf(gc);
      float cn = kt * cp + (1.f - kt) * c_prev;
      float hp = tanhf(cp) * ov;
      float hn = kt * hp + (1.f - kt) * h_prev;
      cS[s] = cn; hS[s] = hn;
      out[((size_t)b * 512 + t) * 768 + ed] = hn;
      __bf16 hv = (__bf16)hn;
      unsigned u = (unsigned)__builtin_bit_cast(unsigned short, hv);
      store_coherent_short(hnxt + b * 768 + ed, u);
    }
    waitcnt_vm0();   // h stores visible at coherence point before arrive

    gridbar(&bar[0], &bar[1]);
  }
}

// ---------------- launch ----------------
extern "C" void kernel_launch(void* const* d_in, const int* in_sizes, int n_in,
                              void* d_out, int out_size, void* d_ws, size_t ws_size,
                              hipStream_t stream) {
  const float* x     = (const float*)d_in[0];
  const float* W     = (const float*)d_in[1];
  const float* U     = (const float*)d_in[2];
  const float* bias  = (const float*)d_in[3];
  const float* wpeep = (const float*)d_in[4];
  const float* tau   = (const float*)d_in[5];
  const float* shift = (const float*)d_in[6];
  float* out = (float*)d_out;
  char* ws = (char*)d_ws;

  int*    bar = (int*)(ws + OFF_BAR);
  __bf16* hb0 = (__bf16*)(ws + OFF_HBUF0);
  __bf16* hb1 = (__bf16*)(ws + OFF_HBUF1);
  float*  kT  = (float*)(ws + OFF_KTAB);
  __bf16* WT  = (__bf16*)(ws + OFF_WT);
  __bf16* xb  = (__bf16*)(ws + OFF_XB);
  int use_xb = (ws_size >= WS_NEED_FULL) ? 1 : 0;

  hipMemsetAsync(ws, 0, OFF_KTAB, stream);
  k_wcomb<<<48 * 96, 256, 0, stream>>>(W, U, WT);
  k_ktab<<<(512 * 768) / 256, 256, 0, stream>>>(tau, shift, kT);
  if (use_xb) k_xb<<<(512 * 64 * 768) / 256, 256, 0, stream>>>(x, xb);
  k_lstm<<<G_BLOCKS, 256, 0, stream>>>(xb, x, use_xb, WT, kT, bias, wpeep,
                                       hb0, hb1, out, bar);
}

// Round 3
// 4296.325 us; speedup vs baseline: 2.8157x; 2.0589x over previous
//
#include <hip/hip_runtime.h>
#include <math.h>

// PhasedLSTM: B=64, T=512, H=768. fp32 in/out.
// Persistent kernel, 1 distributed-flag barrier per timestep.
// R2->R3: (1) barrier = per-block monotonic flags on own cachelines (no RMW,
//   no shared-line polling); (2) B (WT slice) preloaded to LDS once -> clean
//   vmcnt domain, single-latency pipelined h-loads; (3) x@W partial computed
//   pre-barrier, only h@U on the critical path.

#define HDIM 768
#define BDIM 64
#define TDIM 512
#define G_BLOCKS 96
#define ND 8   // hidden dims per block (768/96)

typedef float f32x4 __attribute__((ext_vector_type(4)));
typedef __bf16 bf16x8 __attribute__((ext_vector_type(8)));
typedef int i32x4 __attribute__((ext_vector_type(4)));

// workspace layout (bytes)
#define OFF_FLAGS 0                                     // 96 x 64B lines
#define OFF_HBUF0 8192
#define OFF_HBUF1 (8192 + 98304)
#define OFF_KTAB  (8192 + 2*98304)                      // 204800
#define OFF_WT    (OFF_KTAB + (size_t)512*768*4)        // 1777664
#define OFF_XB    (OFF_WT + (size_t)3072*1536*2)        // 11214848
#define WS_NEED_FULL (OFF_XB + (size_t)512*64*768*2)    // 61546496

// ---------------- prep kernels ----------------

__global__ void k_wcomb(const float* __restrict__ W, const float* __restrict__ U,
                        __bf16* __restrict__ WT) {
  __shared__ __bf16 tile[32][33];
  int tk = blockIdx.x % 48;   // k tile (1536/32)
  int tn = blockIdx.x / 48;   // n tile (3072/32)
  int tx = threadIdx.x & 31, ty = threadIdx.x >> 5; // 32 x 8
  int k0 = tk * 32, n0 = tn * 32;
#pragma unroll
  for (int i = 0; i < 4; ++i) {
    int k = k0 + ty + 8 * i;
    int n = n0 + tx;
    const float* M = (k < 768) ? W : U;
    int r = (k < 768) ? k : k - 768;
    float v;
    if (n < 2304)
      v = M[(size_t)r * 3072 + n] + M[(size_t)(768 + r) * 3072 + n] +
          M[(size_t)(1536 + r) * 3072 + n];
    else
      v = M[(size_t)(2304 + r) * 3072 + n];
    tile[ty + 8 * i][tx] = (__bf16)v;
  }
  __syncthreads();
#pragma unroll
  for (int i = 0; i < 4; ++i) {
    int n = n0 + ty + 8 * i;
    int k = k0 + tx;
    WT[(size_t)n * 1536 + k] = tile[tx][ty + 8 * i];
  }
}

__global__ void k_ktab(const float* __restrict__ tau, const float* __restrict__ shift,
                       float* __restrict__ kT) {
  int idx = blockIdx.x * 256 + threadIdx.x;  // t*768 + d
  int d = idx % 768, t = idx / 768;
  float bb = tau[d];
  float a = (float)t - shift[d];
  const float PI = 3.14159265358979323846f;
  float fm = bb / PI * atanf(tanf(PI * (a / bb - 0.5f))) + bb * 0.5f;
  float phi = fm / (bb + 1e-8f);
  float kv;
  if (phi < 0.5f * 0.05f)      kv = 2.0f * phi / 0.05f;
  else if (phi < 0.05f)        kv = 2.0f - 2.0f * phi / 0.05f;
  else                         kv = 0.001f * phi;
  kT[idx] = kv;
}

__global__ void k_xb(const float* __restrict__ x, __bf16* __restrict__ xb) {
  int idx = blockIdx.x * 256 + threadIdx.x;  // (t*64+b)*768 + k
  int k = idx % 768;
  int tb = idx / 768;
  int b = tb % 64, t = tb / 64;
  xb[idx] = (__bf16)x[((size_t)b * 512 + t) * 768 + k];
}

// ---------------- coherent access helpers ----------------
__device__ __forceinline__ i32x4 ldg_c16(const void* p) {
  i32x4 r;
  asm volatile("global_load_dwordx4 %0, %1, off sc0 sc1" : "=v"(r) : "v"(p));
  return r;
}
__device__ __forceinline__ int ldg_c4_wait(const void* p) {
  int r;
  asm volatile("global_load_dword %0, %1, off sc0 sc1\n\ts_waitcnt vmcnt(0)"
               : "=v"(r) : "v"(p) : "memory");
  return r;
}
__device__ __forceinline__ void stg_c2(void* p, unsigned v) {
  asm volatile("global_store_short %0, %1, off sc0 sc1"
               :: "v"(p), "v"(v) : "memory");
}
__device__ __forceinline__ void stg_c4(void* p, int v) {
  asm volatile("global_store_dword %0, %1, off sc0 sc1"
               :: "v"(p), "v"(v) : "memory");
}
__device__ __forceinline__ void waitcnt_vm0() {
  asm volatile("s_waitcnt vmcnt(0)" ::: "memory");
}
#define HOLD4(x) asm volatile("" : "+v"(x))

// ---------------- persistent recurrent kernel ----------------
__global__ __launch_bounds__(256, 1)
void k_lstm(const __bf16* __restrict__ xb, const float* __restrict__ xf, int use_xb,
            const __bf16* __restrict__ WT, const float* __restrict__ kT,
            const float* __restrict__ bias, const float* __restrict__ wpeep,
            __bf16* h0buf, __bf16* h1buf, float* __restrict__ out, int* flags) {
  const int j = blockIdx.x, d0 = j * ND;
  const int tid = threadIdx.x;
  const int wave = tid >> 6, lane = tid & 63;
  const int quad = lane >> 4, l15 = lane & 15;

  // LDS: B slice (32 cols x 1536 k, stride 1544 for conflict-free b128),
  // gacc partials per wave, block-local c/h state.
  __shared__ __align__(16) __bf16 Bl[32][1544];
  __shared__ float gacc[4][64][36];
  __shared__ float cS[512], hS[512];

  // ---- preload B slice into LDS (once) ----
  for (int idx = tid; idx < 6144; idx += 256) {   // 32 cols * 192 chunks(16B)
    int c = idx / 192, kc = idx % 192;
    int n = (c >> 3) * 768 + d0 + (c & 7);
    *(bf16x8*)&Bl[c][kc * 8] = *(const bf16x8*)&WT[(size_t)n * 1536 + kc * 8];
  }
  for (int s = tid; s < 512; s += 256) { cS[s] = 0.f; hS[s] = 0.f; }

  const int edl = tid & 7, eb0 = tid >> 3;
  const int ed = d0 + edl;
  const float bi  = bias[ed],        bfv = bias[768 + ed];
  const float bo  = bias[1536 + ed], bcv = bias[2304 + ed];
  const float wpi = wpeep[ed], wpf = wpeep[768 + ed], wpo = wpeep[1536 + ed];

  __syncthreads();

  for (int t = 0; t < TDIM; ++t) {
    const __bf16* hcur = (t & 1) ? h1buf : h0buf;
    __bf16* hnxt = (t & 1) ? h0buf : h1buf;

    // ---- x-phase (no barrier dependency): acc += x_t @ W-part ----
    f32x4 acc[4][2];
#pragma unroll
    for (int rt = 0; rt < 4; ++rt) { acc[rt][0] = (f32x4){0,0,0,0}; acc[rt][1] = (f32x4){0,0,0,0}; }
#pragma unroll
    for (int i = 0; i < 6; ++i) {
      const int kk = (wave * 6 + i) * 32 + quad * 8;   // k in [0,768)
      bf16x8 a[4];
      if (use_xb) {
#pragma unroll
        for (int rt = 0; rt < 4; ++rt)
          a[rt] = *(const bf16x8*)(xb + ((size_t)(t * 64 + rt * 16 + l15)) * 768 + kk);
      } else {
#pragma unroll
        for (int rt = 0; rt < 4; ++rt)
#pragma unroll
          for (int q = 0; q < 8; ++q)
            a[rt][q] = (__bf16)xf[((size_t)(rt * 16 + l15) * 512 + t) * 768 + kk + q];
      }
      bf16x8 b0 = *(const bf16x8*)&Bl[l15][kk];
      bf16x8 b1 = *(const bf16x8*)&Bl[16 + l15][kk];
#pragma unroll
      for (int rt = 0; rt < 4; ++rt) {
        acc[rt][0] = __builtin_amdgcn_mfma_f32_16x16x32_bf16(a[rt], b0, acc[rt][0], 0, 0, 0);
        acc[rt][1] = __builtin_amdgcn_mfma_f32_16x16x32_bf16(a[rt], b1, acc[rt][1], 0, 0, 0);
      }
    }

    // ---- barrier wait: all blocks' h_t visible? (flags[j] >= t) ----
    if (tid < G_BLOCKS) {
      const int* fp = flags + tid * 16;   // 64B stride
      while (ldg_c4_wait(fp) < t) __builtin_amdgcn_s_sleep(1);
    }
    __syncthreads();

    // ---- h-phase: issue all 24 coherent h loads, pipelined vmcnt ----
    i32x4 hr[6][4];
#pragma unroll
    for (int i = 0; i < 6; ++i) {
      const int hoff = (wave * 6 + i) * 32 + quad * 8;  // h-dim in [0,768)
#pragma unroll
      for (int rt = 0; rt < 4; ++rt)
        hr[i][rt] = ldg_c16(hcur + (size_t)(rt * 16 + l15) * 768 + hoff);
    }
    asm volatile("s_waitcnt vmcnt(12)");   // first 12 (i=0..2) complete
#pragma unroll
    for (int i = 0; i < 3; ++i) {
#pragma unroll
      for (int rt = 0; rt < 4; ++rt) HOLD4(hr[i][rt]);
      const int kk = 768 + (wave * 6 + i) * 32 + quad * 8;
      bf16x8 b0 = *(const bf16x8*)&Bl[l15][kk];
      bf16x8 b1 = *(const bf16x8*)&Bl[16 + l15][kk];
#pragma unroll
      for (int rt = 0; rt < 4; ++rt) {
        bf16x8 av = __builtin_bit_cast(bf16x8, hr[i][rt]);
        acc[rt][0] = __builtin_amdgcn_mfma_f32_16x16x32_bf16(av, b0, acc[rt][0], 0, 0, 0);
        acc[rt][1] = __builtin_amdgcn_mfma_f32_16x16x32_bf16(av, b1, acc[rt][1], 0, 0, 0);
      }
    }
    asm volatile("s_waitcnt vmcnt(0)");
#pragma unroll
    for (int i = 3; i < 6; ++i) {
#pragma unroll
      for (int rt = 0; rt < 4; ++rt) HOLD4(hr[i][rt]);
      const int kk = 768 + (wave * 6 + i) * 32 + quad * 8;
      bf16x8 b0 = *(const bf16x8*)&Bl[l15][kk];
      bf16x8 b1 = *(const bf16x8*)&Bl[16 + l15][kk];
#pragma unroll
      for (int rt = 0; rt < 4; ++rt) {
        bf16x8 av = __builtin_bit_cast(bf16x8, hr[i][rt]);
        acc[rt][0] = __builtin_amdgcn_mfma_f32_16x16x32_bf16(av, b0, acc[rt][0], 0, 0, 0);
        acc[rt][1] = __builtin_amdgcn_mfma_f32_16x16x32_bf16(av, b1, acc[rt][1], 0, 0, 0);
      }
    }

    // ---- write partials: C/D layout col=lane&15, row=quad*4+reg ----
#pragma unroll
    for (int rt = 0; rt < 4; ++rt)
#pragma unroll
      for (int r = 0; r < 4; ++r) {
        int row = rt * 16 + quad * 4 + r;
        gacc[wave][row][l15]      = acc[rt][0][r];
        gacc[wave][row][16 + l15] = acc[rt][1][r];
      }
    __syncthreads();

    // ---- elementwise update ----
    float kt = kT[t * 768 + ed];
#pragma unroll
    for (int rep = 0; rep < 2; ++rep) {
      int b = eb0 + 32 * rep;
      int s = b * 8 + edl;
      float c_prev = cS[s], h_prev = hS[s];
      float gi = bi + wpi * c_prev, gf = bfv + wpf * c_prev;
      float go = bo + wpo * c_prev, gc = bcv;
#pragma unroll
      for (int w = 0; w < 4; ++w) {
        gi += gacc[w][b][edl];
        gf += gacc[w][b][8 + edl];
        go += gacc[w][b][16 + edl];
        gc += gacc[w][b][24 + edl];
      }
      float iv = 1.f / (1.f + expf(-gi));
      float fv = 1.f / (1.f + expf(-gf));
      float ov = 1.f / (1.f + expf(-go));
      float cp = fv * c_prev + iv * tanhf(gc);
      float cn = kt * cp + (1.f - kt) * c_prev;
      float hp = tanhf(cp) * ov;
      float hn = kt * hp + (1.f - kt) * h_prev;
      cS[s] = cn; hS[s] = hn;
      out[((size_t)b * 512 + t) * 768 + ed] = hn;
      __bf16 hv = (__bf16)hn;
      stg_c2(hnxt + b * 768 + ed, (unsigned)__builtin_bit_cast(unsigned short, hv));
    }
    waitcnt_vm0();            // this thread's h stores at coherence point
    __syncthreads();          // => whole block's h stores visible
    if (t < TDIM - 1 && tid == 0) stg_c4(flags + j * 16, t + 1);  // arrive
  }
}

// ---------------- launch ----------------
extern "C" void kernel_launch(void* const* d_in, const int* in_sizes, int n_in,
                              void* d_out, int out_size, void* d_ws, size_t ws_size,
                              hipStream_t stream) {
  const float* x     = (const float*)d_in[0];
  const float* W     = (const float*)d_in[1];
  const float* U     = (const float*)d_in[2];
  const float* bias  = (const float*)d_in[3];
  const float* wpeep = (const float*)d_in[4];
  const float* tau   = (const float*)d_in[5];
  const float* shift = (const float*)d_in[6];
  float* out = (float*)d_out;
  char* ws = (char*)d_ws;

  int*    flags = (int*)(ws + OFF_FLAGS);
  __bf16* hb0 = (__bf16*)(ws + OFF_HBUF0);
  __bf16* hb1 = (__bf16*)(ws + OFF_HBUF1);
  float*  kT  = (float*)(ws + OFF_KTAB);
  __bf16* WT  = (__bf16*)(ws + OFF_WT);
  __bf16* xb  = (__bf16*)(ws + OFF_XB);
  int use_xb = (ws_size >= WS_NEED_FULL) ? 1 : 0;

  hipMemsetAsync(ws, 0, OFF_KTAB, stream);  // flags + both h buffers = 0
  k_wcomb<<<48 * 96, 256, 0, stream>>>(W, U, WT);
  k_ktab<<<(512 * 768) / 256, 256, 0, stream>>>(tau, shift, kT);
  if (use_xb) k_xb<<<(512 * 64 * 768) / 256, 256, 0, stream>>>(x, xb);
  k_lstm<<<G_BLOCKS, 256, 0, stream>>>(xb, x, use_xb, WT, kT, bias, wpeep,
                                       hb0, hb1, out, flags);
}

// Round 4
// 4194.424 us; speedup vs baseline: 2.8841x; 1.0243x over previous
//
#include <hip/hip_runtime.h>
#include <math.h>

// PhasedLSTM: B=64, T=512, H=768. fp32 in/out.
// Persistent kernel, distributed per-WAVE flag barrier per timestep.
// R3->R4: per-wave flags (no block sync on arrival path), out-stores moved
//   off the critical vmcnt drain (after flag, dwordx2), chunk-major B LDS
//   layout (2-way banks only), gacc transposed for b128 writes, 1-rep
//   elementwise (thread = 1 batch x 2 dims), all loop VMEM as volatile asm
//   so manual vmcnt counts stay exact.

#define HDIM 768
#define BDIM 64
#define TDIM 512
#define G_BLOCKS 96
#define ND 8   // hidden dims per block (768/96)

typedef float f32x4 __attribute__((ext_vector_type(4)));
typedef float f32x2 __attribute__((ext_vector_type(2)));
typedef __bf16 bf16x8 __attribute__((ext_vector_type(8)));
typedef int i32x4 __attribute__((ext_vector_type(4)));
typedef int i32x2 __attribute__((ext_vector_type(2)));

// workspace layout (bytes)
#define OFF_FLAGS 0                                     // 384 x 64B lines
#define OFF_HBUF0 24576
#define OFF_HBUF1 (24576 + 98304)
#define OFF_KTAB  (24576 + 2*98304)                     // 221184
#define OFF_WT    (OFF_KTAB + (size_t)512*768*4)        // + 1.5MB
#define OFF_XB    (OFF_WT + (size_t)3072*1536*2)        // + 9.4MB
#define WS_NEED_FULL (OFF_XB + (size_t)512*64*768*2)    // ~61.6MB

// ---------------- prep kernels ----------------

__global__ void k_wcomb(const float* __restrict__ W, const float* __restrict__ U,
                        __bf16* __restrict__ WT) {
  __shared__ __bf16 tile[32][33];
  int tk = blockIdx.x % 48;   // k tile (1536/32)
  int tn = blockIdx.x / 48;   // n tile (3072/32)
  int tx = threadIdx.x & 31, ty = threadIdx.x >> 5; // 32 x 8
  int k0 = tk * 32, n0 = tn * 32;
#pragma unroll
  for (int i = 0; i < 4; ++i) {
    int k = k0 + ty + 8 * i;
    int n = n0 + tx;
    const float* M = (k < 768) ? W : U;
    int r = (k < 768) ? k : k - 768;
    float v;
    if (n < 2304)
      v = M[(size_t)r * 3072 + n] + M[(size_t)(768 + r) * 3072 + n] +
          M[(size_t)(1536 + r) * 3072 + n];
    else
      v = M[(size_t)(2304 + r) * 3072 + n];
    tile[ty + 8 * i][tx] = (__bf16)v;
  }
  __syncthreads();
#pragma unroll
  for (int i = 0; i < 4; ++i) {
    int n = n0 + ty + 8 * i;
    int k = k0 + tx;
    WT[(size_t)n * 1536 + k] = tile[tx][ty + 8 * i];
  }
}

__global__ void k_ktab(const float* __restrict__ tau, const float* __restrict__ shift,
                       float* __restrict__ kT) {
  int idx = blockIdx.x * 256 + threadIdx.x;  // t*768 + d
  int d = idx % 768, t = idx / 768;
  float bb = tau[d];
  float a = (float)t - shift[d];
  const float PI = 3.14159265358979323846f;
  float fm = bb / PI * atanf(tanf(PI * (a / bb - 0.5f))) + bb * 0.5f;
  float phi = fm / (bb + 1e-8f);
  float kv;
  if (phi < 0.5f * 0.05f)      kv = 2.0f * phi / 0.05f;
  else if (phi < 0.05f)        kv = 2.0f - 2.0f * phi / 0.05f;
  else                         kv = 0.001f * phi;
  kT[idx] = kv;
}

__global__ void k_xb(const float* __restrict__ x, __bf16* __restrict__ xb) {
  int idx = blockIdx.x * 256 + threadIdx.x;  // (t*64+b)*768 + k
  int k = idx % 768;
  int tb = idx / 768;
  int b = tb % 64, t = tb / 64;
  xb[idx] = (__bf16)x[((size_t)b * 512 + t) * 768 + k];
}

// ---------------- asm memory helpers ----------------
__device__ __forceinline__ i32x4 ldg_c16(const void* p) {
  i32x4 r;
  asm volatile("global_load_dwordx4 %0, %1, off sc0 sc1" : "=v"(r) : "v"(p));
  return r;
}
__device__ __forceinline__ i32x2 ldg_n8(const void* p) {
  i32x2 r;
  asm volatile("global_load_dwordx2 %0, %1, off" : "=v"(r) : "v"(p));
  return r;
}
__device__ __forceinline__ void stg_c4(void* p, int v) {
  asm volatile("global_store_dword %0, %1, off sc0 sc1"
               :: "v"(p), "v"(v) : "memory");
}
__device__ __forceinline__ void stg_n8(void* p, i32x2 v) {
  asm volatile("global_store_dwordx2 %0, %1, off"
               :: "v"(p), "v"(v) : "memory");
}
__device__ __forceinline__ void waitcnt_vm0() {
  asm volatile("s_waitcnt vmcnt(0)" ::: "memory");
}
#define HOLD4(x) asm volatile("" : "+v"(x))

// ---------------- persistent recurrent kernel ----------------
__global__ __launch_bounds__(256, 1)
void k_lstm(const __bf16* __restrict__ xb, const float* __restrict__ xf, int use_xb,
            const __bf16* __restrict__ WT, const float* __restrict__ kT,
            const float* __restrict__ bias, const float* __restrict__ wpeep,
            __bf16* h0buf, __bf16* h1buf, float* __restrict__ out, int* flags) {
  const int j = blockIdx.x, d0 = j * ND;
  const int tid = threadIdx.x;
  const int wave = tid >> 6, lane = tid & 63;
  const int quad = lane >> 4, l15 = lane & 15;

  // LDS: B slice chunk-major (kc-chunk of 8 k, 32 cols, 16B each);
  // gacc col-major (b128 writes); block-local c/h state.
  __shared__ __align__(16) __bf16 Bl2[192 * 32 * 8];
  __shared__ float gacc2[4][32][68];
  __shared__ float cS[512], hS[512];

  // ---- preload B slice into LDS (once) ----
  for (int idx = tid; idx < 6144; idx += 256) {  // idx = kc*32 + c
    int c = idx & 31, kc = idx >> 5;
    int n = (c >> 3) * 768 + d0 + (c & 7);
    *(bf16x8*)&Bl2[(size_t)idx * 8] = *(const bf16x8*)&WT[(size_t)n * 1536 + kc * 8];
  }
  for (int s = tid; s < 512; s += 256) { cS[s] = 0.f; hS[s] = 0.f; }

  // elementwise mapping: thread = (batch bb, dim-pair dq)
  const int dq = tid & 3, bb = tid >> 2;
  const int ed0 = d0 + dq * 2;
  const f32x2 bi2  = *(const f32x2*)&bias[ed0];
  const f32x2 bf2  = *(const f32x2*)&bias[768 + ed0];
  const f32x2 bo2  = *(const f32x2*)&bias[1536 + ed0];
  const f32x2 bc2  = *(const f32x2*)&bias[2304 + ed0];
  const f32x2 wpi2 = *(const f32x2*)&wpeep[ed0];
  const f32x2 wpf2 = *(const f32x2*)&wpeep[768 + ed0];
  const f32x2 wpo2 = *(const f32x2*)&wpeep[1536 + ed0];

  // poll set: wave w consumes dims [w*192,(w+1)*192) = blocks [w*24,(w+1)*24),
  // all 4 waves each -> flag ids [w*96, (w+1)*96)
  const int fid0 = wave * 96 + lane;
  const int fid1 = wave * 96 + 64 + (lane & 31);
  const int* fp0 = flags + fid0 * 16;
  const int* fp1 = flags + fid1 * 16;

  __syncthreads();

  for (int t = 0; t < TDIM; ++t) {
    const __bf16* hcur = (t & 1) ? h1buf : h0buf;
    __bf16* hnxt = (t & 1) ? h0buf : h1buf;

    // ---- kT prefetch (asm; drained by poll's vmcnt0) ----
    i32x2 ktraw = ldg_n8(kT + (size_t)t * 768 + ed0);

    // ---- x-phase (no barrier dependency): acc += x_t @ W-part ----
    f32x4 acc[4][2];
#pragma unroll
    for (int rt = 0; rt < 4; ++rt) { acc[rt][0] = (f32x4){0,0,0,0}; acc[rt][1] = (f32x4){0,0,0,0}; }
#pragma unroll
    for (int i = 0; i < 6; ++i) {
      const int kk = (wave * 6 + i) * 32 + quad * 8;   // k in [0,768)
      const int kc = kk >> 3;
      bf16x8 a[4];
      if (use_xb) {
#pragma unroll
        for (int rt = 0; rt < 4; ++rt)
          a[rt] = *(const bf16x8*)(xb + ((size_t)(t * 64 + rt * 16 + l15)) * 768 + kk);
      } else {
#pragma unroll
        for (int rt = 0; rt < 4; ++rt)
#pragma unroll
          for (int q = 0; q < 8; ++q)
            a[rt][q] = (__bf16)xf[((size_t)(rt * 16 + l15) * 512 + t) * 768 + kk + q];
      }
      bf16x8 b0 = *(const bf16x8*)&Bl2[(size_t)(kc * 32 + l15) * 8];
      bf16x8 b1 = *(const bf16x8*)&Bl2[(size_t)(kc * 32 + 16 + l15) * 8];
#pragma unroll
      for (int rt = 0; rt < 4; ++rt) {
        acc[rt][0] = __builtin_amdgcn_mfma_f32_16x16x32_bf16(a[rt], b0, acc[rt][0], 0, 0, 0);
        acc[rt][1] = __builtin_amdgcn_mfma_f32_16x16x32_bf16(a[rt], b1, acc[rt][1], 0, 0, 0);
      }
    }

    // ---- per-wave poll: my producers' h_t visible? ----
    for (;;) {
      int v0, v1;
      asm volatile("global_load_dword %0, %2, off sc0 sc1\n\t"
                   "global_load_dword %1, %3, off sc0 sc1\n\t"
                   "s_waitcnt vmcnt(0)"
                   : "=v"(v0), "=v"(v1) : "v"(fp0), "v"(fp1) : "memory");
      if (__all(v0 >= t && v1 >= t)) break;
      __builtin_amdgcn_s_sleep(1);
    }

    // ---- h-phase: 24 coherent loads, pipelined vmcnt (exact counts) ----
    i32x4 hr[6][4];
#pragma unroll
    for (int i = 0; i < 6; ++i) {
      const int hoff = (wave * 6 + i) * 32 + quad * 8;  // h-dim in [0,768)
#pragma unroll
      for (int rt = 0; rt < 4; ++rt)
        hr[i][rt] = ldg_c16(hcur + (size_t)(rt * 16 + l15) * 768 + hoff);
    }
    asm volatile("s_waitcnt vmcnt(12)");   // first 12 (i=0..2) complete
#pragma unroll
    for (int i = 0; i < 3; ++i) {
#pragma unroll
      for (int rt = 0; rt < 4; ++rt) HOLD4(hr[i][rt]);
      const int kc = 96 + (wave * 6 + i) * 4 + quad;
      bf16x8 b0 = *(const bf16x8*)&Bl2[(size_t)(kc * 32 + l15) * 8];
      bf16x8 b1 = *(const bf16x8*)&Bl2[(size_t)(kc * 32 + 16 + l15) * 8];
#pragma unroll
      for (int rt = 0; rt < 4; ++rt) {
        bf16x8 av = __builtin_bit_cast(bf16x8, hr[i][rt]);
        acc[rt][0] = __builtin_amdgcn_mfma_f32_16x16x32_bf16(av, b0, acc[rt][0], 0, 0, 0);
        acc[rt][1] = __builtin_amdgcn_mfma_f32_16x16x32_bf16(av, b1, acc[rt][1], 0, 0, 0);
      }
    }
    asm volatile("s_waitcnt vmcnt(0)");
#pragma unroll
    for (int i = 3; i < 6; ++i) {
#pragma unroll
      for (int rt = 0; rt < 4; ++rt) HOLD4(hr[i][rt]);
      const int kc = 96 + (wave * 6 + i) * 4 + quad;
      bf16x8 b0 = *(const bf16x8*)&Bl2[(size_t)(kc * 32 + l15) * 8];
      bf16x8 b1 = *(const bf16x8*)&Bl2[(size_t)(kc * 32 + 16 + l15) * 8];
#pragma unroll
      for (int rt = 0; rt < 4; ++rt) {
        bf16x8 av = __builtin_bit_cast(bf16x8, hr[i][rt]);
        acc[rt][0] = __builtin_amdgcn_mfma_f32_16x16x32_bf16(av, b0, acc[rt][0], 0, 0, 0);
        acc[rt][1] = __builtin_amdgcn_mfma_f32_16x16x32_bf16(av, b1, acc[rt][1], 0, 0, 0);
      }
    }

    // ---- write partials (col-major, b128): C/D col=lane&15, row=quad*4+reg
#pragma unroll
    for (int rt = 0; rt < 4; ++rt) {
      *(f32x4*)&gacc2[wave][l15][rt * 16 + quad * 4]      = acc[rt][0];
      *(f32x4*)&gacc2[wave][16 + l15][rt * 16 + quad * 4] = acc[rt][1];
    }
    __syncthreads();

    // ---- elementwise update (1 rep: thread = batch bb, dims ed0,ed0+1) ----
    f32x2 kt2 = __builtin_bit_cast(f32x2, ktraw);
    float gs[2][4];
#pragma unroll
    for (int dd = 0; dd < 2; ++dd)
#pragma unroll
      for (int g = 0; g < 4; ++g) {
        float s = 0.f;
#pragma unroll
        for (int w = 0; w < 4; ++w) s += gacc2[w][g * 8 + dq * 2 + dd][bb];
        gs[dd][g] = s;
      }
    f32x2 cpv = *(const f32x2*)&cS[bb * 8 + dq * 2];
    f32x2 hpv = *(const f32x2*)&hS[bb * 8 + dq * 2];
    f32x2 cnv, hnv;
#pragma unroll
    for (int dd = 0; dd < 2; ++dd) {
      float c_prev = cpv[dd], h_prev = hpv[dd], kt = kt2[dd];
      float gi = gs[dd][0] + bi2[dd] + wpi2[dd] * c_prev;
      float gf = gs[dd][1] + bf2[dd] + wpf2[dd] * c_prev;
      float go = gs[dd][2] + bo2[dd] + wpo2[dd] * c_prev;
      float gc = gs[dd][3] + bc2[dd];
      float iv = 1.f / (1.f + expf(-gi));
      float fv = 1.f / (1.f + expf(-gf));
      float ov = 1.f / (1.f + expf(-go));
      float cp = fv * c_prev + iv * tanhf(gc);
      float cn = kt * cp + (1.f - kt) * c_prev;
      float hp = tanhf(cp) * ov;
      float hn = kt * hp + (1.f - kt) * h_prev;
      cnv[dd] = cn; hnv[dd] = hn;
    }
    *(f32x2*)&cS[bb * 8 + dq * 2] = cnv;
    *(f32x2*)&hS[bb * 8 + dq * 2] = hnv;

    // h store (coherent, packed dword), drain, arrive, then out (deferred)
    __bf16 h0 = (__bf16)hnv[0], h1 = (__bf16)hnv[1];
    unsigned hu = (unsigned)__builtin_bit_cast(unsigned short, h0) |
                  ((unsigned)__builtin_bit_cast(unsigned short, h1) << 16);
    stg_c4(hnxt + (size_t)bb * 768 + ed0, (int)hu);
    waitcnt_vm0();                       // wave-wide: h stores at coherence pt
    __syncthreads();                     // gacc2 read/write hazard across steps
    if (tid < 4) stg_c4(flags + (j * 4 + tid) * 16, t + 1);
    f32x2 ov2; ov2[0] = hnv[0]; ov2[1] = hnv[1];
    stg_n8(out + ((size_t)bb * 512 + t) * 768 + ed0, __builtin_bit_cast(i32x2, ov2));
  }
}

// ---------------- launch ----------------
extern "C" void kernel_launch(void* const* d_in, const int* in_sizes, int n_in,
                              void* d_out, int out_size, void* d_ws, size_t ws_size,
                              hipStream_t stream) {
  const float* x     = (const float*)d_in[0];
  const float* W     = (const float*)d_in[1];
  const float* U     = (const float*)d_in[2];
  const float* bias  = (const float*)d_in[3];
  const float* wpeep = (const float*)d_in[4];
  const float* tau   = (const float*)d_in[5];
  const float* shift = (const float*)d_in[6];
  float* out = (float*)d_out;
  char* ws = (char*)d_ws;

  int*    flags = (int*)(ws + OFF_FLAGS);
  __bf16* hb0 = (__bf16*)(ws + OFF_HBUF0);
  __bf16* hb1 = (__bf16*)(ws + OFF_HBUF1);
  float*  kT  = (float*)(ws + OFF_KTAB);
  __bf16* WT  = (__bf16*)(ws + OFF_WT);
  __bf16* xb  = (__bf16*)(ws + OFF_XB);
  int use_xb = (ws_size >= WS_NEED_FULL) ? 1 : 0;

  hipMemsetAsync(ws, 0, OFF_KTAB, stream);  // flags + both h buffers = 0
  k_wcomb<<<48 * 96, 256, 0, stream>>>(W, U, WT);
  k_ktab<<<(512 * 768) / 256, 256, 0, stream>>>(tau, shift, kT);
  if (use_xb) k_xb<<<(512 * 64 * 768) / 256, 256, 0, stream>>>(x, xb);
  k_lstm<<<G_BLOCKS, 256, 0, stream>>>(xb, x, use_xb, WT, kT, bias, wpeep,
                                       hb0, hb1, out, flags);
}